// Round 8
// baseline (146.427 us; speedup 1.0000x reference)
//
#include <hip/hip_runtime.h>

// DistributionLoss: local 7x7xC std (zero-padded) of two [16,3,512,512] fp32
// tensors, smooth-L1 mean between std maps -> scalar.
//
// R8: R7's two-phase LDS design with phase A explicitly software-pipelined.
//  - Each thread owns 3 tasks (608 tasks / 256 threads, 3rd predicated).
//  - Loads for tasks 0+1 issue before task 0's compute; task 2's loads
//    issue before task 1's compute -> >=9 float4 loads always in flight.
//  - Bounded 3-stage pipeline, named-member structs only (no arrays, no
//    component pointers): VGPR ~140, no spill under launch_bounds(256,2).
//  - Phase B (vertical 7-tap + std + fused smooth-L1) unchanged from R7.

#define K     7
#define PAD   3
#define TSX   64
#define TSY   32
#define HR    (TSY + K - 1)   // 38 halo rows
#define LDSW  68              // LDS row stride (floats)
#define NT    256
#define NTASK (HR * 16)       // 608

struct T9   { float4 A0, B0, C0, A1, B1, C1, A2, B2, C2; };
struct TaskD { int row, cg, gyc, gx0; float m; bool lOK, rOK; };

__device__ __forceinline__ float4 ld4(const float* p) { return *(const float4*)p; }

__device__ __forceinline__ float4 add3(float4 a, float4 b, float4 c) {
    return make_float4(a.x + b.x + c.x, a.y + b.y + c.y,
                       a.z + b.z + c.z, a.w + b.w + c.w);
}
__device__ __forceinline__ float4 sq3(float4 a, float4 b, float4 c) {
    return make_float4(fmaf(a.x, a.x, fmaf(b.x, b.x, c.x * c.x)),
                       fmaf(a.y, a.y, fmaf(b.y, b.y, c.y * c.y)),
                       fmaf(a.z, a.z, fmaf(b.z, b.z, c.z * c.z)),
                       fmaf(a.w, a.w, fmaf(b.w, b.w, c.w * c.w)));
}

__device__ __forceinline__ TaskD decode(int task, int tx0, int ty0) {
    TaskD d;
    d.row = task >> 4;
    d.cg  = task & 15;
    int gy = ty0 - PAD + d.row;
    d.m   = ((unsigned)gy < 512u) ? 1.0f : 0.0f;
    d.gyc = min(max(gy, 0), 511);
    d.gx0 = tx0 + (d.cg << 2);
    d.lOK = (d.gx0 > 0);
    d.rOK = (d.gx0 < 508);
    return d;
}

__device__ __forceinline__ T9 load9(const float* base, size_t plane, TaskD d) {
    const float4 z4 = make_float4(0.f, 0.f, 0.f, 0.f);
    const float* r0 = base + (size_t)d.gyc * 512 + d.gx0;
    const float* r1 = r0 + plane;
    const float* r2 = r1 + plane;
    T9 t;
    t.A0 = d.lOK ? ld4(r0 - 4) : z4;  t.B0 = ld4(r0);  t.C0 = d.rOK ? ld4(r0 + 4) : z4;
    t.A1 = d.lOK ? ld4(r1 - 4) : z4;  t.B1 = ld4(r1);  t.C1 = d.rOK ? ld4(r1 + 4) : z4;
    t.A2 = d.lOK ? ld4(r2 - 4) : z4;  t.B2 = ld4(r2);  t.C2 = d.rOK ? ld4(r2 + 4) : z4;
    return t;
}

__device__ __forceinline__ void hstore(T9 t, TaskD d,
                                       float (*sh_s)[LDSW], float (*sh_q)[LDSW]) {
    float4 tl = add3(t.A0, t.A1, t.A2);
    float4 tm = add3(t.B0, t.B1, t.B2);
    float4 tr = add3(t.C0, t.C1, t.C2);
    float4 ul = sq3(t.A0, t.A1, t.A2);
    float4 um = sq3(t.B0, t.B1, t.B2);
    float4 ur = sq3(t.C0, t.C1, t.C2);

    float h0 = tl.y + tl.z + tl.w + tm.x + tm.y + tm.z + tm.w;
    float h1 = h0 - tl.y + tr.x;
    float h2 = h1 - tl.z + tr.y;
    float h3 = h2 - tl.w + tr.z;
    float g0 = ul.y + ul.z + ul.w + um.x + um.y + um.z + um.w;
    float g1 = g0 - ul.y + ur.x;
    float g2 = g1 - ul.z + ur.y;
    float g3 = g2 - ul.w + ur.z;

    *(float4*)&sh_s[d.row][d.cg << 2] =
        make_float4(h0 * d.m, h1 * d.m, h2 * d.m, h3 * d.m);
    *(float4*)&sh_q[d.row][d.cg << 2] =
        make_float4(g0 * d.m, g1 * d.m, g2 * d.m, g3 * d.m);
}

__global__ __launch_bounds__(NT, 2) void dist_loss_kernel(
    const float* __restrict__ pred,
    const float* __restrict__ tgt,
    float* __restrict__ out)
{
    constexpr int   C = 3, H = 512, W = 512;
    constexpr float INV_N     = 1.0f / (C * K * K);              // 1/147
    constexpr float INV_TOTAL = 1.0f / (16.0f * 512.0f * 512.0f);

    __shared__ float sh_s[HR][LDSW];
    __shared__ float sh_q[HR][LDSW];

    const int    tid  = threadIdx.x;
    const int    tx0  = blockIdx.x * TSX;
    const int    ty0  = blockIdx.y * TSY;
    const int    b    = blockIdx.z;
    const size_t plane = (size_t)H * W;
    const float4 z4 = make_float4(0.f, 0.f, 0.f, 0.f);

    const int  t2v = tid + 2 * NT;
    const bool v2  = (t2v < NTASK);

    const TaskD d0 = decode(tid,            tx0, ty0);
    const TaskD d1 = decode(tid + NT,       tx0, ty0);
    const TaskD d2 = decode(v2 ? t2v : tid, tx0, ty0);   // clamped: harmless reload

    float4 pA, pB;            // input 0's std quads
    float  acc = 0.0f;

    #pragma unroll
    for (int which = 0; which < 2; ++which) {
        const float* base = (which == 0 ? pred : tgt) + (size_t)b * C * plane;

        // ---- Phase A: pipelined global -> horizontal 7-tap -> LDS
        {
            T9 x0 = load9(base, plane, d0);
            T9 x1 = load9(base, plane, d1);
            hstore(x0, d0, sh_s, sh_q);
            T9 x2 = load9(base, plane, d2);
            hstore(x1, d1, sh_s, sh_q);
            if (v2) hstore(x2, d2, sh_s, sh_q);
        }
        __syncthreads();

        // ---- Phase B: vertical 7-tap + std; 2 output rows per thread
        {
            const int rp = tid >> 4;          // row pair 0..15
            const int x  = (tid & 15) << 2;   // col within tile

            float4 S = z4, Q = z4;
            #pragma unroll
            for (int k = 0; k < K; ++k) {
                float4 hv = *(const float4*)&sh_s[2 * rp + k][x];
                float4 gv = *(const float4*)&sh_q[2 * rp + k][x];
                S.x += hv.x; S.y += hv.y; S.z += hv.z; S.w += hv.w;
                Q.x += gv.x; Q.y += gv.y; Q.z += gv.z; Q.w += gv.w;
            }
            float4 hA = *(const float4*)&sh_s[2 * rp][x];
            float4 gA = *(const float4*)&sh_q[2 * rp][x];
            float4 hB = *(const float4*)&sh_s[2 * rp + 7][x];
            float4 gB = *(const float4*)&sh_q[2 * rp + 7][x];
            float4 S2 = make_float4(S.x - hA.x + hB.x, S.y - hA.y + hB.y,
                                    S.z - hA.z + hB.z, S.w - hA.w + hB.w);
            float4 Q2 = make_float4(Q.x - gA.x + gB.x, Q.y - gA.y + gB.y,
                                    Q.z - gA.z + gB.z, Q.w - gA.w + gB.w);

            #define STD4(Sv, Qv, D)                                           \
                {                                                             \
                    float mux = (Sv).x * INV_N, muy = (Sv).y * INV_N,         \
                          muz = (Sv).z * INV_N, muw = (Sv).w * INV_N;         \
                    (D).x = sqrtf(fmaf(-mux, mux, (Qv).x * INV_N) + 1e-8f);   \
                    (D).y = sqrtf(fmaf(-muy, muy, (Qv).y * INV_N) + 1e-8f);   \
                    (D).z = sqrtf(fmaf(-muz, muz, (Qv).z * INV_N) + 1e-8f);   \
                    (D).w = sqrtf(fmaf(-muw, muw, (Qv).w * INV_N) + 1e-8f);   \
                }
            #define SL1(a, bb)                                                \
                {                                                             \
                    float d  = (a) - (bb);                                    \
                    float ad = fabsf(d);                                      \
                    acc += (ad < 1.0f) ? 0.5f * d * d : (ad - 0.5f);          \
                }

            if (which == 0) {
                STD4(S, Q, pA);
                STD4(S2, Q2, pB);
            } else {
                float4 sA, sB;
                STD4(S, Q, sA);
                STD4(S2, Q2, sB);
                SL1(pA.x, sA.x); SL1(pA.y, sA.y);
                SL1(pA.z, sA.z); SL1(pA.w, sA.w);
                SL1(pB.x, sB.x); SL1(pB.y, sB.y);
                SL1(pB.z, sB.z); SL1(pB.w, sB.w);
            }
            #undef STD4
            #undef SL1
        }
        __syncthreads();   // protect sh_s/sh_q before next input's phase A
    }

    // ---- block reduction: wave64 shuffle, cross-wave via LDS, one atomic
    #pragma unroll
    for (int off = 32; off > 0; off >>= 1)
        acc += __shfl_down(acc, off, 64);

    __shared__ float wave_sums[NT / 64];
    if ((tid & 63) == 0) wave_sums[tid >> 6] = acc;
    __syncthreads();
    if (tid == 0) {
        float s = 0.0f;
        #pragma unroll
        for (int w = 0; w < NT / 64; ++w) s += wave_sums[w];
        atomicAdd(out, s * INV_TOTAL);
    }
}

extern "C" void kernel_launch(void* const* d_in, const int* in_sizes, int n_in,
                              void* d_out, int out_size, void* d_ws, size_t ws_size,
                              hipStream_t stream) {
    const float* pred = (const float*)d_in[0];
    const float* tgt  = (const float*)d_in[1];
    float* out = (float*)d_out;

    hipMemsetAsync(out, 0, sizeof(float), stream);

    dim3 grid(512 / TSX, 512 / TSY, 16);   // 8 x 16 x 16 = 2048 blocks
    dist_loss_kernel<<<grid, NT, 0, stream>>>(pred, tgt, out);
}